// Round 13
// baseline (231.632 us; speedup 1.0000x reference)
//
#include <hip/hip_runtime.h>
#include <hip/hip_bf16.h>

#define HEADS 4
#define CH    32
#define HC    128
#define FIN   128
#define NG    64
#define POOL_CHUNKS 8
#define CAP   64    // max in-degree bucket capacity (Poisson(17): P(>64) < 1e-18)

typedef __bf16 bf16x8 __attribute__((ext_vector_type(8)));
typedef float  f32x4  __attribute__((ext_vector_type(4)));

// ---------------------------------------------------------------------------
// K0: WT[n][k] = bf16(W[k][n])  (one-time 128x128 transpose+convert)
// ---------------------------------------------------------------------------
__global__ void wtrans_kernel(const float* __restrict__ W,
                              __hip_bfloat16* __restrict__ WT) {
    int t = blockIdx.x * 256 + threadIdx.x;
    if (t < HC * FIN) {
        int n = t >> 7, k = t & 127;
        WT[n * FIN + k] = __float2bfloat16(W[k * HC + n]);
    }
}

// ---------------------------------------------------------------------------
// K1: xb = bf16(x @ W) via bf16 MFMA + fused attention logits.
// 128-row tile (was 64): halves per-block W re-staging, amortizes barriers.
// Wave wv owns rows [wv*32, wv*32+32) as two 16-row m-tiles.
// Logit reduction via shfl_xor butterfly (width 16) — no LDS scratch
// (also fixes the old 2KB scratch overrun past Wl).
// ---------------------------------------------------------------------------
__global__ __launch_bounds__(256) void proj_mfma_kernel(const float* __restrict__ x,
                                                        const __hip_bfloat16* __restrict__ WT,
                                                        const float* __restrict__ att_src,
                                                        const float* __restrict__ att_dst,
                                                        __hip_bfloat16* __restrict__ xb,
                                                        float* __restrict__ a_src,
                                                        float* __restrict__ a_dst,
                                                        int N) {
    __shared__ char Xl[128 * 256];   // 32 KB: [row][16 granules][16B], swizzled
    __shared__ char Wl[128 * 256];   // 32 KB: [n][16 granules][16B], swizzled
    int t = threadIdx.x;
    int base = blockIdx.x * 128;

    // stage X (fp32 -> bf16): 128 rows x 16 granules
    for (int v = t; v < 2048; v += 256) {
        int row = v >> 4, g = v & 15;
        int node = base + row;
        union { bf16x8 v8; uint4 u4; } tmp;
        if (node < N) {
            float4 f0 = *(const float4*)&x[(size_t)node * FIN + g * 8];
            float4 f1 = *(const float4*)&x[(size_t)node * FIN + g * 8 + 4];
            tmp.v8[0] = (__bf16)f0.x; tmp.v8[1] = (__bf16)f0.y;
            tmp.v8[2] = (__bf16)f0.z; tmp.v8[3] = (__bf16)f0.w;
            tmp.v8[4] = (__bf16)f1.x; tmp.v8[5] = (__bf16)f1.y;
            tmp.v8[6] = (__bf16)f1.z; tmp.v8[7] = (__bf16)f1.w;
        } else {
            tmp.u4 = make_uint4(0, 0, 0, 0);
        }
        int gs = g ^ (row & 7);
        *(uint4*)&Xl[row * 256 + gs * 16] = tmp.u4;
    }
    // stage WT (already bf16): 128 n-rows x 16 granules
    for (int v = t; v < 2048; v += 256) {
        int n = v >> 4, g = v & 15;
        uint4 u = *(const uint4*)&WT[n * FIN + g * 8];
        int gs = g ^ (n & 7);
        *(uint4*)&Wl[n * 256 + gs * 16] = u;
    }
    __syncthreads();

    int wv = t >> 6, lane = t & 63;
    int lr = lane & 15, lg = lane >> 4;
    f32x4 acc[2][8];
#pragma unroll
    for (int m = 0; m < 2; m++)
#pragma unroll
        for (int tt = 0; tt < 8; tt++) acc[m][tt] = (f32x4){0.f, 0.f, 0.f, 0.f};

#pragma unroll
    for (int kc = 0; kc < 4; kc++) {
        int ga = (kc * 4 + lg) ^ (lr & 7);
        bf16x8 a0 = *(bf16x8*)&Xl[(wv * 32 + lr) * 256 + ga * 16];
        bf16x8 a1 = *(bf16x8*)&Xl[(wv * 32 + 16 + lr) * 256 + ga * 16];
#pragma unroll
        for (int tt = 0; tt < 8; tt++) {
            int nr = tt * 16 + lr;
            int gb = (kc * 4 + lg) ^ (lr & 7);
            bf16x8 b = *(bf16x8*)&Wl[nr * 256 + gb * 16];
            acc[0][tt] = __builtin_amdgcn_mfma_f32_16x16x32_bf16(a0, b, acc[0][tt], 0, 0, 0);
            acc[1][tt] = __builtin_amdgcn_mfma_f32_16x16x32_bf16(a1, b, acc[1][tt], 0, 0, 0);
        }
    }

    // epilogue per m-tile: store xb + shuffle-reduced attention logits
#pragma unroll
    for (int m = 0; m < 2; m++) {
        float ps[4][4], pd[4][4];
#pragma unroll
        for (int r = 0; r < 4; r++)
#pragma unroll
            for (int h = 0; h < 4; h++) { ps[r][h] = 0.f; pd[r][h] = 0.f; }

        int rowbase = base + wv * 32 + m * 16 + lg * 4;
#pragma unroll
        for (int tt = 0; tt < 8; tt++) {
            int h = tt >> 1;
            int c = (tt & 1) * 16 + lr;
            float sv = att_src[h * CH + c];
            float dv = att_dst[h * CH + c];
            int col = tt * 16 + lr;
#pragma unroll
            for (int r = 0; r < 4; r++) {
                int row = rowbase + r;
                float v = acc[m][tt][r];
                if (row < N) xb[(size_t)row * HC + col] = __float2bfloat16(v);
                ps[r][h] += v * sv;
                pd[r][h] += v * dv;
            }
        }
        // butterfly reduce over the 16 lr lanes (width 16 keeps groups intact)
#pragma unroll
        for (int mask = 1; mask < 16; mask <<= 1) {
#pragma unroll
            for (int r = 0; r < 4; r++)
#pragma unroll
                for (int h = 0; h < 4; h++) {
                    ps[r][h] += __shfl_xor(ps[r][h], mask, 16);
                    pd[r][h] += __shfl_xor(pd[r][h], mask, 16);
                }
        }
        // lane lr writes (r,h) = (lr>>2, lr&3): 16 contiguous floats per group
        {
            int r = lr >> 2, h = lr & 3;
            int node = rowbase + r;
            if (node < N) {
                a_src[node * 4 + h] = ps[r][h];
                a_dst[node * 4 + h] = pd[r][h];
            }
        }
    }
}

// ---------------------------------------------------------------------------
// K3: bucket edges by destination (REVERTED to round-11 winner: 4 chains,
// plain ushort stores — NT stores cost +16 µs, R12 post-mortem).
// ---------------------------------------------------------------------------
__global__ __launch_bounds__(256) void csr_scatter(const int* __restrict__ esrc,
                                                   const int* __restrict__ edst,
                                                   int* __restrict__ cnt,
                                                   unsigned short* __restrict__ bucket,
                                                   int E, int EN) {
    int b = blockIdx.x * 1024 + threadIdx.x;
    int i0 = b, i1 = b + 256, i2 = b + 512, i3 = b + 768;
    int s0, d0, s1, d1, s2, d2, s3, d3;
    bool v0 = i0 < EN, v1 = i1 < EN, v2 = i2 < EN, v3 = i3 < EN;
    if (v0) { if (i0 < E) { s0 = esrc[i0]; d0 = edst[i0]; } else { s0 = d0 = i0 - E; } }
    if (v1) { if (i1 < E) { s1 = esrc[i1]; d1 = edst[i1]; } else { s1 = d1 = i1 - E; } }
    if (v2) { if (i2 < E) { s2 = esrc[i2]; d2 = edst[i2]; } else { s2 = d2 = i2 - E; } }
    if (v3) { if (i3 < E) { s3 = esrc[i3]; d3 = edst[i3]; } else { s3 = d3 = i3 - E; } }
    int p0, p1, p2, p3;
    if (v0) p0 = atomicAdd(&cnt[d0], 1);
    if (v1) p1 = atomicAdd(&cnt[d1], 1);
    if (v2) p2 = atomicAdd(&cnt[d2], 1);
    if (v3) p3 = atomicAdd(&cnt[d3], 1);
    if (v0 && p0 < CAP) bucket[(size_t)d0 * CAP + p0] = (unsigned short)s0;
    if (v1 && p1 < CAP) bucket[(size_t)d1 * CAP + p1] = (unsigned short)s1;
    if (v2 && p2 < CAP) bucket[(size_t)d2 * CAP + p2] = (unsigned short)s2;
    if (v3 && p3 < CAP) bucket[(size_t)d3 * CAP + p3] = (unsigned short)s3;
}

// ---------------------------------------------------------------------------
// K4: wave-per-node gather aggregation (unchanged; ushort bucket).
// ---------------------------------------------------------------------------
__global__ __launch_bounds__(256) void agg_wave_kernel(const int* __restrict__ cnt,
                                                       const unsigned short* __restrict__ bucket,
                                                       const float* __restrict__ a_src,
                                                       const float* __restrict__ a_dst,
                                                       const __hip_bfloat16* __restrict__ xb,
                                                       float* __restrict__ agg, int N) {
    __shared__ int   sid[4][CAP];
    __shared__ float sw[4][CAP * 4];
    int wv = threadIdx.x >> 6;
    int lane = threadIdx.x & 63;
    int d = blockIdx.x * 4 + wv;
    if (d >= N) return;                 // wave-uniform exit; no barriers used
    int deg = min(cnt[d], CAP);         // deg >= 1 (self loop)
    const unsigned short* lst = bucket + (size_t)d * CAP;

    if (lane < deg) sid[wv][lane] = lst[lane];

    float adh = a_dst[d * 4 + (lane & 3)];
    float wpart = 0.f;
    for (int p = lane; p < deg * 4; p += 64) {
        int i = p >> 2;
        int s = sid[wv][i];
        float e = a_src[s * 4 + (lane & 3)] + adh;
        e = e >= 0.f ? e : 0.2f * e;
        float w = __expf(e);
        sw[wv][p] = w;
        wpart += w;
    }
#pragma unroll
    for (int off = 4; off < 64; off <<= 1) wpart += __shfl_xor(wpart, off, 64);
    float rdc = 1.0f / fmaxf(wpart, 1e-16f);
    int h = lane >> 4;
    float rd = __shfl(rdc, h, 64);

    int j0 = lane * 2;
    float n0 = 0.f, n1 = 0.f;
    int i = 0;
    for (; i + 4 <= deg; i += 4) {
        int s0 = sid[wv][i], s1 = sid[wv][i + 1];
        int s2 = sid[wv][i + 2], s3 = sid[wv][i + 3];
        unsigned u0 = *(const unsigned*)&xb[(size_t)s0 * HC + j0];
        unsigned u1 = *(const unsigned*)&xb[(size_t)s1 * HC + j0];
        unsigned u2 = *(const unsigned*)&xb[(size_t)s2 * HC + j0];
        unsigned u3 = *(const unsigned*)&xb[(size_t)s3 * HC + j0];
        float w0 = sw[wv][(i + 0) * 4 + h], w1 = sw[wv][(i + 1) * 4 + h];
        float w2 = sw[wv][(i + 2) * 4 + h], w3 = sw[wv][(i + 3) * 4 + h];
        n0 += w0 * __uint_as_float(u0 << 16) + w1 * __uint_as_float(u1 << 16)
            + w2 * __uint_as_float(u2 << 16) + w3 * __uint_as_float(u3 << 16);
        n1 += w0 * __uint_as_float(u0 & 0xffff0000u) + w1 * __uint_as_float(u1 & 0xffff0000u)
            + w2 * __uint_as_float(u2 & 0xffff0000u) + w3 * __uint_as_float(u3 & 0xffff0000u);
    }
    for (; i < deg; i++) {
        int s0 = sid[wv][i];
        unsigned u0 = *(const unsigned*)&xb[(size_t)s0 * HC + j0];
        float w0 = sw[wv][i * 4 + h];
        n0 += w0 * __uint_as_float(u0 << 16);
        n1 += w0 * __uint_as_float(u0 & 0xffff0000u);
    }
    float2 o = make_float2(n0 * rd, n1 * rd);
    *(float2*)&agg[(size_t)d * HC + j0] = o;
}

// ---------------------------------------------------------------------------
// K5: segmented mean-pool (batch sorted; binary-search graph bounds).
// ---------------------------------------------------------------------------
__global__ __launch_bounds__(256) void pool_kernel(const float* __restrict__ agg,
                                                   const float* __restrict__ bias,
                                                   const int* __restrict__ batch,
                                                   float* __restrict__ pooled,
                                                   float* __restrict__ counts, int N) {
    int g = blockIdx.x / POOL_CHUNKS;
    int chunk = blockIdx.x % POOL_CHUNKS;
    int t = threadIdx.x;

    int lo = 0, hi = N;
    while (lo < hi) { int mid = (lo + hi) >> 1; if (batch[mid] < g) lo = mid + 1; else hi = mid; }
    int gstart = lo;
    hi = N;
    while (lo < hi) { int mid = (lo + hi) >> 1; if (batch[mid] < g + 1) lo = mid + 1; else hi = mid; }
    int gend = lo;
    int cnt = gend - gstart;

    int per = (cnt + POOL_CHUNKS - 1) / POOL_CHUNKS;
    int cstart = gstart + chunk * per;
    int cend = min(cstart + per, gend);

    int col = t & 31;
    int row = t >> 5;
    float4 b4 = *(const float4*)&bias[col * 4];
    float4 acc = make_float4(0.f, 0.f, 0.f, 0.f);
    for (int n = cstart + row; n < cend; n += 8) {
        float4 v = *(const float4*)&agg[(size_t)n * HC + col * 4];
        acc.x += fmaxf(v.x + b4.x, 0.f);
        acc.y += fmaxf(v.y + b4.y, 0.f);
        acc.z += fmaxf(v.z + b4.z, 0.f);
        acc.w += fmaxf(v.w + b4.w, 0.f);
    }

    __shared__ float4 red[256];
    red[t] = acc;
    __syncthreads();
    if (t < 128) {
        red[t].x += red[t + 128].x; red[t].y += red[t + 128].y;
        red[t].z += red[t + 128].z; red[t].w += red[t + 128].w;
    }
    __syncthreads();
    if (t < 64) {
        red[t].x += red[t + 64].x; red[t].y += red[t + 64].y;
        red[t].z += red[t + 64].z; red[t].w += red[t + 64].w;
    }
    __syncthreads();
    if (t < 32) {
        float4 r = red[t];
        r.x += red[t + 32].x; r.y += red[t + 32].y;
        r.z += red[t + 32].z; r.w += red[t + 32].w;
        atomicAdd(&pooled[g * HC + t * 4 + 0], r.x);
        atomicAdd(&pooled[g * HC + t * 4 + 1], r.y);
        atomicAdd(&pooled[g * HC + t * 4 + 2], r.z);
        atomicAdd(&pooled[g * HC + t * 4 + 3], r.w);
    }
    if (t == 0 && chunk == 0) counts[g] = (float)cnt;
}

// ---------------------------------------------------------------------------
// K6: out[g][o] = (sum_k pooled[g][k] * W_lin[k][o]) / count[g] + b_lin[o]
// ---------------------------------------------------------------------------
__global__ void final_kernel(const float* __restrict__ pooled,
                             const float* __restrict__ counts,
                             const float* __restrict__ W_lin,
                             const float* __restrict__ b_lin,
                             float* __restrict__ out) {
    int t = threadIdx.x;
    int g = t >> 1, o = t & 1;
    float cnt = fmaxf(counts[g], 1.f);
    float sum = 0.f;
#pragma unroll 8
    for (int k = 0; k < HC; k++) sum += pooled[g * HC + k] * W_lin[k * 2 + o];
    out[g * 2 + o] = sum / cnt + b_lin[o];
}

extern "C" void kernel_launch(void* const* d_in, const int* in_sizes, int n_in,
                              void* d_out, int out_size, void* d_ws, size_t ws_size,
                              hipStream_t stream) {
    const float* x       = (const float*)d_in[0];
    const int*   eidx    = (const int*)d_in[1];
    const int*   batch   = (const int*)d_in[2];
    const float* W       = (const float*)d_in[3];
    const float* att_src = (const float*)d_in[4];
    const float* att_dst = (const float*)d_in[5];
    const float* bias    = (const float*)d_in[6];
    const float* W_lin   = (const float*)d_in[7];
    const float* b_lin   = (const float*)d_in[8];
    float* out = (float*)d_out;

    int N  = in_sizes[0] / FIN;
    int E  = in_sizes[1] / 2;
    int EN = E + N;
    const int* esrc = eidx;
    const int* edst = eidx + E;

    char* wsb = (char*)d_ws;
    __hip_bfloat16* xb = (__hip_bfloat16*)wsb; wsb += (size_t)N * HC * 2;
    float* a_src  = (float*)wsb;          wsb += (size_t)N * 4 * 4;
    float* a_dst  = (float*)wsb;          wsb += (size_t)N * 4 * 4;
    float* agg    = (float*)wsb;          wsb += (size_t)N * HC * 4;
    float* pooled = (float*)wsb;          wsb += (size_t)NG * HC * 4;
    float* counts = (float*)wsb;          wsb += (size_t)NG * 4;
    int*   cnt    = (int*)wsb;            wsb += (size_t)N * 4;
    unsigned short* bucket = (unsigned short*)wsb; wsb += (size_t)N * CAP * 2;
    __hip_bfloat16* WT = (__hip_bfloat16*)wsb; wsb += (size_t)HC * FIN * 2;

    hipMemsetAsync(cnt, 0, (size_t)N * sizeof(int), stream);
    hipMemsetAsync(pooled, 0, (size_t)(NG * HC + NG) * sizeof(float), stream);

    wtrans_kernel<<<(HC * FIN + 255) / 256, 256, 0, stream>>>(W, WT);
    proj_mfma_kernel<<<(N + 127) / 128, 256, 0, stream>>>(x, WT, att_src, att_dst,
                                                          xb, a_src, a_dst, N);
    csr_scatter<<<(EN + 1023) / 1024, 256, 0, stream>>>(esrc, edst, cnt, bucket, E, EN);
    agg_wave_kernel<<<(N + 3) / 4, 256, 0, stream>>>(cnt, bucket, a_src, a_dst, xb, agg, N);
    pool_kernel<<<NG * POOL_CHUNKS, 256, 0, stream>>>(agg, bias, batch, pooled, counts, N);
    final_kernel<<<1, 128, 0, stream>>>(pooled, counts, W_lin, b_lin, out);
}

// Round 14
// 207.539 us; speedup vs baseline: 1.1161x; 1.1161x over previous
//
#include <hip/hip_runtime.h>
#include <hip/hip_bf16.h>

#define HEADS 4
#define CH    32
#define HC    128
#define FIN   128
#define NG    64
#define POOL_CHUNKS 8
#define CAP   64    // max in-degree bucket capacity (Poisson(17): P(>64) < 1e-18)

typedef __bf16 bf16x8 __attribute__((ext_vector_type(8)));
typedef float  f32x4  __attribute__((ext_vector_type(4)));

// ---------------------------------------------------------------------------
// K0: WT[n][k] = bf16(W[k][n])  (one-time 128x128 transpose+convert)
// ---------------------------------------------------------------------------
__global__ void wtrans_kernel(const float* __restrict__ W,
                              __hip_bfloat16* __restrict__ WT) {
    int t = blockIdx.x * 256 + threadIdx.x;
    if (t < HC * FIN) {
        int n = t >> 7, k = t & 127;
        WT[n * FIN + k] = __float2bfloat16(W[k * HC + n]);
    }
}

// ---------------------------------------------------------------------------
// K1: xb = bf16(x @ W) via bf16 MFMA + fused attention logits.
// REVERTED to the 64-row R11 structure (128-row tile cost +31 µs, R13
// post-mortem). Scratch now properly carved from one 48 KB smem block
// (fixes R11's 2 KB overrun past Wl): after the MFMA phase completes,
// the Xl+Wl region is dead and the 34.8 KB logit scratch reuses it.
// ---------------------------------------------------------------------------
__global__ __launch_bounds__(256) void proj_mfma_kernel(const float* __restrict__ x,
                                                        const __hip_bfloat16* __restrict__ WT,
                                                        const float* __restrict__ att_src,
                                                        const float* __restrict__ att_dst,
                                                        __hip_bfloat16* __restrict__ xb,
                                                        float* __restrict__ a_src,
                                                        float* __restrict__ a_dst,
                                                        int N) {
    __shared__ char smem[48 * 1024];
    char* Xl = smem;               // 16 KB: [row][16 granules][16B], swizzled
    char* Wl = smem + 16 * 1024;   // 32 KB: [n][16 granules][16B], swizzled
    int t = threadIdx.x;
    int base = blockIdx.x * 64;

    for (int v = t; v < 1024; v += 256) {
        int row = v >> 4, g = v & 15;
        int node = base + row;
        union { bf16x8 v8; uint4 u4; } tmp;
        if (node < N) {
            float4 f0 = *(const float4*)&x[(size_t)node * FIN + g * 8];
            float4 f1 = *(const float4*)&x[(size_t)node * FIN + g * 8 + 4];
            tmp.v8[0] = (__bf16)f0.x; tmp.v8[1] = (__bf16)f0.y;
            tmp.v8[2] = (__bf16)f0.z; tmp.v8[3] = (__bf16)f0.w;
            tmp.v8[4] = (__bf16)f1.x; tmp.v8[5] = (__bf16)f1.y;
            tmp.v8[6] = (__bf16)f1.z; tmp.v8[7] = (__bf16)f1.w;
        } else {
            tmp.u4 = make_uint4(0, 0, 0, 0);
        }
        int gs = g ^ (row & 7);
        *(uint4*)&Xl[row * 256 + gs * 16] = tmp.u4;
    }
    for (int v = t; v < 2048; v += 256) {
        int n = v >> 4, g = v & 15;
        uint4 u = *(const uint4*)&WT[n * FIN + g * 8];
        int gs = g ^ (n & 7);
        *(uint4*)&Wl[n * 256 + gs * 16] = u;
    }
    __syncthreads();

    int wv = t >> 6, lane = t & 63;
    int lr = lane & 15, lg = lane >> 4;
    f32x4 acc[8];
#pragma unroll
    for (int tt = 0; tt < 8; tt++) acc[tt] = (f32x4){0.f, 0.f, 0.f, 0.f};

#pragma unroll
    for (int kc = 0; kc < 4; kc++) {
        int rowl = wv * 16 + lr;
        int ga = (kc * 4 + lg) ^ (lr & 7);
        bf16x8 a = *(bf16x8*)&Xl[rowl * 256 + ga * 16];
#pragma unroll
        for (int tt = 0; tt < 8; tt++) {
            int nr = tt * 16 + lr;
            int gb = (kc * 4 + lg) ^ (lr & 7);
            bf16x8 b = *(bf16x8*)&Wl[nr * 256 + gb * 16];
            acc[tt] = __builtin_amdgcn_mfma_f32_16x16x32_bf16(a, b, acc[tt], 0, 0, 0);
        }
    }

    float ps[4][4];
    float pd[4][4];
#pragma unroll
    for (int r = 0; r < 4; r++)
#pragma unroll
        for (int h = 0; h < 4; h++) { ps[r][h] = 0.f; pd[r][h] = 0.f; }

#pragma unroll
    for (int tt = 0; tt < 8; tt++) {
        int h = tt >> 1;
        int c = (tt & 1) * 16 + lr;
        float sv = att_src[h * CH + c];
        float dv = att_dst[h * CH + c];
        int col = tt * 16 + lr;
#pragma unroll
        for (int r = 0; r < 4; r++) {
            int row = base + wv * 16 + lg * 4 + r;
            float v = acc[tt][r];
            if (row < N) xb[(size_t)row * HC + col] = __float2bfloat16(v);
            ps[r][h] += v * sv;
            pd[r][h] += v * dv;
        }
    }

    // logit reduction over the 16 lr lanes via LDS scratch (reuses smem;
    // MFMA phase is done). ssrc/sdst: 64 rows x 68 floats = 17408 B each.
    __syncthreads();
    float* ssrc = (float*)smem;
    float* sdst = (float*)(smem + 17408);
#pragma unroll
    for (int r = 0; r < 4; r++) {
        int rowl = wv * 16 + lg * 4 + r;
#pragma unroll
        for (int h = 0; h < 4; h++) {
            ssrc[rowl * 68 + lr * 4 + h] = ps[r][h];
            sdst[rowl * 68 + lr * 4 + h] = pd[r][h];
        }
    }
    __syncthreads();
    {
        int rowl = t >> 2, h = t & 3;
        int node = base + rowl;
        float ss = 0.f, sd = 0.f;
#pragma unroll
        for (int q = 0; q < 16; q++) {
            ss += ssrc[rowl * 68 + q * 4 + h];
            sd += sdst[rowl * 68 + q * 4 + h];
        }
        if (node < N) {
            a_src[node * 4 + h] = ss;
            a_dst[node * 4 + h] = sd;
        }
    }
}

// ---------------------------------------------------------------------------
// K3: bucket edges by destination (round-11 winner: 4 independent
// atomicAdd->store chains, plain ushort stores).
// ---------------------------------------------------------------------------
__global__ __launch_bounds__(256) void csr_scatter(const int* __restrict__ esrc,
                                                   const int* __restrict__ edst,
                                                   int* __restrict__ cnt,
                                                   unsigned short* __restrict__ bucket,
                                                   int E, int EN) {
    int b = blockIdx.x * 1024 + threadIdx.x;
    int i0 = b, i1 = b + 256, i2 = b + 512, i3 = b + 768;
    int s0, d0, s1, d1, s2, d2, s3, d3;
    bool v0 = i0 < EN, v1 = i1 < EN, v2 = i2 < EN, v3 = i3 < EN;
    if (v0) { if (i0 < E) { s0 = esrc[i0]; d0 = edst[i0]; } else { s0 = d0 = i0 - E; } }
    if (v1) { if (i1 < E) { s1 = esrc[i1]; d1 = edst[i1]; } else { s1 = d1 = i1 - E; } }
    if (v2) { if (i2 < E) { s2 = esrc[i2]; d2 = edst[i2]; } else { s2 = d2 = i2 - E; } }
    if (v3) { if (i3 < E) { s3 = esrc[i3]; d3 = edst[i3]; } else { s3 = d3 = i3 - E; } }
    int p0, p1, p2, p3;
    if (v0) p0 = atomicAdd(&cnt[d0], 1);
    if (v1) p1 = atomicAdd(&cnt[d1], 1);
    if (v2) p2 = atomicAdd(&cnt[d2], 1);
    if (v3) p3 = atomicAdd(&cnt[d3], 1);
    if (v0 && p0 < CAP) bucket[(size_t)d0 * CAP + p0] = (unsigned short)s0;
    if (v1 && p1 < CAP) bucket[(size_t)d1 * CAP + p1] = (unsigned short)s1;
    if (v2 && p2 < CAP) bucket[(size_t)d2 * CAP + p2] = (unsigned short)s2;
    if (v3 && p3 < CAP) bucket[(size_t)d3 * CAP + p3] = (unsigned short)s3;
}

// ---------------------------------------------------------------------------
// K4: wave-per-node gather aggregation. Gather unroll deepened 4 -> 8
// (8 outstanding random-line loads per lane to hide L3 latency).
// ---------------------------------------------------------------------------
__global__ __launch_bounds__(256) void agg_wave_kernel(const int* __restrict__ cnt,
                                                       const unsigned short* __restrict__ bucket,
                                                       const float* __restrict__ a_src,
                                                       const float* __restrict__ a_dst,
                                                       const __hip_bfloat16* __restrict__ xb,
                                                       float* __restrict__ agg, int N) {
    __shared__ int   sid[4][CAP];
    __shared__ float sw[4][CAP * 4];
    int wv = threadIdx.x >> 6;
    int lane = threadIdx.x & 63;
    int d = blockIdx.x * 4 + wv;
    if (d >= N) return;                 // wave-uniform exit; no barriers used
    int deg = min(cnt[d], CAP);         // deg >= 1 (self loop)
    const unsigned short* lst = bucket + (size_t)d * CAP;

    if (lane < deg) sid[wv][lane] = lst[lane];

    float adh = a_dst[d * 4 + (lane & 3)];
    float wpart = 0.f;
    for (int p = lane; p < deg * 4; p += 64) {
        int i = p >> 2;
        int s = sid[wv][i];
        float e = a_src[s * 4 + (lane & 3)] + adh;
        e = e >= 0.f ? e : 0.2f * e;
        float w = __expf(e);
        sw[wv][p] = w;
        wpart += w;
    }
#pragma unroll
    for (int off = 4; off < 64; off <<= 1) wpart += __shfl_xor(wpart, off, 64);
    float rdc = 1.0f / fmaxf(wpart, 1e-16f);
    int h = lane >> 4;
    float rd = __shfl(rdc, h, 64);

    int j0 = lane * 2;
    float n0 = 0.f, n1 = 0.f;
    int i = 0;
    for (; i + 8 <= deg; i += 8) {
        unsigned u[8];
        float w[8];
#pragma unroll
        for (int q = 0; q < 8; q++) {
            int s = sid[wv][i + q];
            u[q] = *(const unsigned*)&xb[(size_t)s * HC + j0];
            w[q] = sw[wv][(i + q) * 4 + h];
        }
#pragma unroll
        for (int q = 0; q < 8; q++) {
            n0 += w[q] * __uint_as_float(u[q] << 16);
            n1 += w[q] * __uint_as_float(u[q] & 0xffff0000u);
        }
    }
    for (; i + 4 <= deg; i += 4) {
        int s0 = sid[wv][i], s1 = sid[wv][i + 1];
        int s2 = sid[wv][i + 2], s3 = sid[wv][i + 3];
        unsigned u0 = *(const unsigned*)&xb[(size_t)s0 * HC + j0];
        unsigned u1 = *(const unsigned*)&xb[(size_t)s1 * HC + j0];
        unsigned u2 = *(const unsigned*)&xb[(size_t)s2 * HC + j0];
        unsigned u3 = *(const unsigned*)&xb[(size_t)s3 * HC + j0];
        float w0 = sw[wv][(i + 0) * 4 + h], w1 = sw[wv][(i + 1) * 4 + h];
        float w2 = sw[wv][(i + 2) * 4 + h], w3 = sw[wv][(i + 3) * 4 + h];
        n0 += w0 * __uint_as_float(u0 << 16) + w1 * __uint_as_float(u1 << 16)
            + w2 * __uint_as_float(u2 << 16) + w3 * __uint_as_float(u3 << 16);
        n1 += w0 * __uint_as_float(u0 & 0xffff0000u) + w1 * __uint_as_float(u1 & 0xffff0000u)
            + w2 * __uint_as_float(u2 & 0xffff0000u) + w3 * __uint_as_float(u3 & 0xffff0000u);
    }
    for (; i < deg; i++) {
        int s0 = sid[wv][i];
        unsigned u0 = *(const unsigned*)&xb[(size_t)s0 * HC + j0];
        float w0 = sw[wv][i * 4 + h];
        n0 += w0 * __uint_as_float(u0 << 16);
        n1 += w0 * __uint_as_float(u0 & 0xffff0000u);
    }
    float2 o = make_float2(n0 * rd, n1 * rd);
    *(float2*)&agg[(size_t)d * HC + j0] = o;
}

// ---------------------------------------------------------------------------
// K5: segmented mean-pool (batch sorted; binary-search graph bounds).
// ---------------------------------------------------------------------------
__global__ __launch_bounds__(256) void pool_kernel(const float* __restrict__ agg,
                                                   const float* __restrict__ bias,
                                                   const int* __restrict__ batch,
                                                   float* __restrict__ pooled,
                                                   float* __restrict__ counts, int N) {
    int g = blockIdx.x / POOL_CHUNKS;
    int chunk = blockIdx.x % POOL_CHUNKS;
    int t = threadIdx.x;

    int lo = 0, hi = N;
    while (lo < hi) { int mid = (lo + hi) >> 1; if (batch[mid] < g) lo = mid + 1; else hi = mid; }
    int gstart = lo;
    hi = N;
    while (lo < hi) { int mid = (lo + hi) >> 1; if (batch[mid] < g + 1) lo = mid + 1; else hi = mid; }
    int gend = lo;
    int cnt = gend - gstart;

    int per = (cnt + POOL_CHUNKS - 1) / POOL_CHUNKS;
    int cstart = gstart + chunk * per;
    int cend = min(cstart + per, gend);

    int col = t & 31;
    int row = t >> 5;
    float4 b4 = *(const float4*)&bias[col * 4];
    float4 acc = make_float4(0.f, 0.f, 0.f, 0.f);
    for (int n = cstart + row; n < cend; n += 8) {
        float4 v = *(const float4*)&agg[(size_t)n * HC + col * 4];
        acc.x += fmaxf(v.x + b4.x, 0.f);
        acc.y += fmaxf(v.y + b4.y, 0.f);
        acc.z += fmaxf(v.z + b4.z, 0.f);
        acc.w += fmaxf(v.w + b4.w, 0.f);
    }

    __shared__ float4 red[256];
    red[t] = acc;
    __syncthreads();
    if (t < 128) {
        red[t].x += red[t + 128].x; red[t].y += red[t + 128].y;
        red[t].z += red[t + 128].z; red[t].w += red[t + 128].w;
    }
    __syncthreads();
    if (t < 64) {
        red[t].x += red[t + 64].x; red[t].y += red[t + 64].y;
        red[t].z += red[t + 64].z; red[t].w += red[t + 64].w;
    }
    __syncthreads();
    if (t < 32) {
        float4 r = red[t];
        r.x += red[t + 32].x; r.y += red[t + 32].y;
        r.z += red[t + 32].z; r.w += red[t + 32].w;
        atomicAdd(&pooled[g * HC + t * 4 + 0], r.x);
        atomicAdd(&pooled[g * HC + t * 4 + 1], r.y);
        atomicAdd(&pooled[g * HC + t * 4 + 2], r.z);
        atomicAdd(&pooled[g * HC + t * 4 + 3], r.w);
    }
    if (t == 0 && chunk == 0) counts[g] = (float)cnt;
}

// ---------------------------------------------------------------------------
// K6: out[g][o] = (sum_k pooled[g][k] * W_lin[k][o]) / count[g] + b_lin[o]
// ---------------------------------------------------------------------------
__global__ void final_kernel(const float* __restrict__ pooled,
                             const float* __restrict__ counts,
                             const float* __restrict__ W_lin,
                             const float* __restrict__ b_lin,
                             float* __restrict__ out) {
    int t = threadIdx.x;
    int g = t >> 1, o = t & 1;
    float cnt = fmaxf(counts[g], 1.f);
    float sum = 0.f;
#pragma unroll 8
    for (int k = 0; k < HC; k++) sum += pooled[g * HC + k] * W_lin[k * 2 + o];
    out[g * 2 + o] = sum / cnt + b_lin[o];
}

extern "C" void kernel_launch(void* const* d_in, const int* in_sizes, int n_in,
                              void* d_out, int out_size, void* d_ws, size_t ws_size,
                              hipStream_t stream) {
    const float* x       = (const float*)d_in[0];
    const int*   eidx    = (const int*)d_in[1];
    const int*   batch   = (const int*)d_in[2];
    const float* W       = (const float*)d_in[3];
    const float* att_src = (const float*)d_in[4];
    const float* att_dst = (const float*)d_in[5];
    const float* bias    = (const float*)d_in[6];
    const float* W_lin   = (const float*)d_in[7];
    const float* b_lin   = (const float*)d_in[8];
    float* out = (float*)d_out;

    int N  = in_sizes[0] / FIN;
    int E  = in_sizes[1] / 2;
    int EN = E + N;
    const int* esrc = eidx;
    const int* edst = eidx + E;

    char* wsb = (char*)d_ws;
    __hip_bfloat16* xb = (__hip_bfloat16*)wsb; wsb += (size_t)N * HC * 2;
    float* a_src  = (float*)wsb;          wsb += (size_t)N * 4 * 4;
    float* a_dst  = (float*)wsb;          wsb += (size_t)N * 4 * 4;
    float* agg    = (float*)wsb;          wsb += (size_t)N * HC * 4;
    float* pooled = (float*)wsb;          wsb += (size_t)NG * HC * 4;
    float* counts = (float*)wsb;          wsb += (size_t)NG * 4;
    int*   cnt    = (int*)wsb;            wsb += (size_t)N * 4;
    unsigned short* bucket = (unsigned short*)wsb; wsb += (size_t)N * CAP * 2;
    __hip_bfloat16* WT = (__hip_bfloat16*)wsb; wsb += (size_t)HC * FIN * 2;

    hipMemsetAsync(cnt, 0, (size_t)N * sizeof(int), stream);
    hipMemsetAsync(pooled, 0, (size_t)(NG * HC + NG) * sizeof(float), stream);

    wtrans_kernel<<<(HC * FIN + 255) / 256, 256, 0, stream>>>(W, WT);
    proj_mfma_kernel<<<(N + 63) / 64, 256, 0, stream>>>(x, WT, att_src, att_dst,
                                                        xb, a_src, a_dst, N);
    csr_scatter<<<(EN + 1023) / 1024, 256, 0, stream>>>(esrc, edst, cnt, bucket, E, EN);
    agg_wave_kernel<<<(N + 3) / 4, 256, 0, stream>>>(cnt, bucket, a_src, a_dst, xb, agg, N);
    pool_kernel<<<NG * POOL_CHUNKS, 256, 0, stream>>>(agg, bias, batch, pooled, counts, N);
    final_kernel<<<1, 128, 0, stream>>>(pooled, counts, W_lin, b_lin, out);
}